// Round 17
// baseline (483.682 us; speedup 1.0000x reference)
//
#include <hip/hip_runtime.h>
#include <hip/hip_bf16.h>

typedef unsigned short u16;
typedef _Float16 f16x8 __attribute__((ext_vector_type(8)));
typedef _Float16 f16x2 __attribute__((ext_vector_type(2)));
typedef float f32x4 __attribute__((ext_vector_type(4)));

#if __has_builtin(__builtin_amdgcn_exp2f)
#define EXP2F(x) __builtin_amdgcn_exp2f(x)
#else
#define EXP2F(x) exp2f(x)
#endif
// log2(e)/32 : p = exp2(acc * FA_C32) = exp(acc/32)
#define FA_C32 0.045084220027780106f

__device__ __forceinline__ f32x4 mfma16h(f16x8 a, f16x8 b, f32x4 c) {
  return __builtin_amdgcn_mfma_f32_16x16x32_f16(a, b, c, 0, 0, 0);
}
__device__ __forceinline__ unsigned pk2h(float a, float b) {
  union { _Float16 h[2]; unsigned u; } x;
  x.h[0] = (_Float16)a; x.h[1] = (_Float16)b;
  return x.u;
}
__device__ __forceinline__ u16 h1(float a) {
  union { _Float16 h; u16 u; } x; x.h = (_Float16)a; return x.u;
}

#if __has_builtin(__builtin_amdgcn_fdot2)
__device__ __forceinline__ float fdot2_(f16x2 a, f16x2 b, float c) {
  return __builtin_amdgcn_fdot2(a, b, c, false);
}
#else
__device__ __forceinline__ float fdot2_(f16x2 a, f16x2 b, float c) {
  return c + (float)a[0] * (float)b[0] + (float)a[1] * (float)b[1];
}
#endif

typedef __attribute__((address_space(1))) const unsigned int gas_u32;
typedef __attribute__((address_space(3))) unsigned int las_u32;
__device__ __forceinline__ void gl_lds16(const u16* g, u16* l) {
  __builtin_amdgcn_global_load_lds((gas_u32*)g, (las_u32*)l, 16, 0, 0);
}

// ---------------- fused cast fp32 -> f16 for X then W, 8 elems/thread ----------------
__global__ __launch_bounds__(256) void cast_f16_k(const float* __restrict__ X,
                                                  u16* __restrict__ Xf,
                                                  const float* __restrict__ W,
                                                  u16* __restrict__ Wf,
                                                  int nX8, int nTot8) {
  int i = blockIdx.x * 256 + threadIdx.x;
  if (i >= nTot8) return;
  const float4* s4;
  uint4* d4;
  if (i < nX8) {
    s4 = (const float4*)X + i * 2;
    d4 = (uint4*)Xf + i;
  } else {
    s4 = (const float4*)W + (i - nX8) * 2;
    d4 = (uint4*)Wf + (i - nX8);
  }
  float4 a = s4[0], b = s4[1];
  uint4 o;
  o.x = pk2h(a.x, a.y); o.y = pk2h(a.z, a.w);
  o.z = pk2h(b.x, b.y); o.w = pk2h(b.z, b.w);
  *d4 = o;
}

// =================================================================
// Round-17: ring-3 LDS, BK=32, ONE barrier per K-tile.
// BM=BN=256, 8 waves (2Mx4N wave tile 128x64), acc 8x4.
// LDS per operand: 3 slots x [128 phys rows][8 x 16B] (16KB/slot, 96KB total).
//   Packing: phys row p, slot s: s' = s ^ (p&7); real row r = p + 128*(s'>>2);
//   k-block kb = s'&3 (8 u16). Bijection (r,kb)<->(p,s). Reads keep the
//   proven 2-way-free bank pattern; gl_lds16 dest stays linear (rule #21:
//   source pre-swizzled, read applies same map).
// Per tile u (slot sl=u%3), single phase:
//   stage tile u+2 -> slot (u+2)%3 (4 gl_lds16/wave: A 2 + B 2)
//   read a[8], b[4] (12 ds_read_b128) | LGKM0 | 32 MFMA (setprio) |
//   VMC(4) [VMC(0) at u+2==NT] | BAR
// Ledger:
//   WAR: stage target slot (u+2)%3 == (u-1)%3; its reads were LGKM0'd by
//        every wave BEFORE BAR(u-1), which precedes this stage issue.
//   RAW: slot u%3 staged at tile u-2; VMC(4)+BAR at end of u-1 drained it
//        (FIFO: outstanding 8 -> 4 each tile; prologue 8 -> VMC4; tails 4->0).
//   lgkm: only the 12 ds_reads count (gl_lds is vmcnt-only); LGKM0+sched_bar
//        fences MFMA (rule #18).
// Waves free-run between barriers -> 2 waves/SIMD overlap reads with MFMA.
//   EPI=0: D0 f16 = exp(acc/32) (clamped)
//   EPI=1: Df f32 = acc / l_row  (l via fdot2 on A-fragments, wn==0 waves)
//   EPI=2: QKV scatter (Q,K row-major; V -> Vt[b][d][s])
// =================================================================
template <int K_, int EPI>
__global__ __launch_bounds__(512, 1) void gemm8p(
    const u16* __restrict__ A, const u16* __restrict__ B,
    const float* __restrict__ bias, u16* __restrict__ D0, u16* __restrict__ D1,
    u16* __restrict__ D2, float* __restrict__ Df, const int ldc,
    const size_t strA, const size_t strB, const size_t strC) {
  constexpr int NT = K_ / 32;
  static_assert(NT >= 4, "need >=4 K-tiles");
  __shared__ __align__(16) u16 As3[3][128 * 64];   // [slot][16KB]
  __shared__ __align__(16) u16 Bs3[3][128 * 64];
  __shared__ float lds_l[256];                     // EPI=1 row sums

  const int tid = threadIdx.x, lane = tid & 63, wid = tid >> 6;
  const int l15 = lane & 15, lhi = lane >> 4;
  const int m0 = blockIdx.x * 256, n0 = blockIdx.y * 256;
  const int wm = wid >> 2, wn = wid & 3;
  const u16* Ag = A + (size_t)blockIdx.z * strA;
  const u16* Bg = B + (size_t)blockIdx.z * strB;

// stage one operand tile (16KB = 256 rows x 32 k): 2 issues per wave.
// lane i of issue q: phys row p = wid*16+q*8+(i>>3), slot s = i&7;
// s' = s^(p&7) = (i&7)^((i>>3)&7) (wave base is 8-row aligned);
// source row = GROW0 + p + 128*(s'>>2), k = T*32 + (s'&3)*8.
#define STAGE_OP(BUF, G, GROW0, T)                                        \
  {                                                                       \
    _Pragma("unroll") for (int q_ = 0; q_ < 2; ++q_) {                    \
      const int bp_ = wid * 16 + q_ * 8;                                  \
      const int p_ = bp_ + (lane >> 3);                                   \
      const int sp_ = (lane & 7) ^ (p_ & 7);                              \
      const int r_ = p_ + 128 * (sp_ >> 2);                               \
      gl_lds16((G) + (size_t)((GROW0) + r_) * K_ + (T) * 32 + (sp_ & 3) * 8, \
               (BUF) + bp_ * 64);                                         \
    }                                                                     \
  }

#define BAR()                                                             \
  asm volatile("" ::: "memory");                                          \
  __builtin_amdgcn_s_barrier();                                           \
  asm volatile("" ::: "memory")

#define LGKM0()                                                           \
  asm volatile("s_waitcnt lgkmcnt(0)" ::: "memory");                      \
  __builtin_amdgcn_sched_barrier(0)

#define SB0() __builtin_amdgcn_sched_barrier(0)
#define VMC4() asm volatile("s_waitcnt vmcnt(4)" ::: "memory")
#define VMC0() asm volatile("s_waitcnt vmcnt(0)" ::: "memory")

  // precomputed per-lane read offsets (u16 units) into a slot:
  // row r, k-block lhi: p = r&127, s = ((r>>7)*4 + lhi) ^ (p&7);
  // offset = p*64 + s*8.
  int offA[8], offB[4];
#pragma unroll
  for (int mf = 0; mf < 8; ++mf) {
    const int r_ = wm * 128 + mf * 16 + l15;
    const int p_ = r_ & 127;
    const int s_ = (((r_ >> 7) << 2) + lhi) ^ (p_ & 7);
    offA[mf] = p_ * 64 + s_ * 8;
  }
#pragma unroll
  for (int nf = 0; nf < 4; ++nf) {
    const int r_ = wn * 64 + nf * 16 + l15;
    const int p_ = r_ & 127;
    const int s_ = (((r_ >> 7) << 2) + lhi) ^ (p_ & 7);
    offB[nf] = p_ * 64 + s_ * 8;
  }

  f32x4 acc[8][4];
#pragma unroll
  for (int i = 0; i < 8; ++i)
#pragma unroll
    for (int j = 0; j < 4; ++j) acc[i][j] = 0.f;

  float lsa[2][4];
#pragma unroll
  for (int i = 0; i < 2; ++i)
#pragma unroll
    for (int j = 0; j < 4; ++j) lsa[i][j] = 0.f;
  const f16x2 ones2 = {(_Float16)1.0f, (_Float16)1.0f};

  // prologue: tiles 0,1 -> slots 0,1 (8 loads/wave); VMC4 drains tile0.
  STAGE_OP(&As3[0][0], Ag, m0, 0);
  STAGE_OP(&Bs3[0][0], Bg, n0, 0);
  STAGE_OP(&As3[1][0], Ag, m0, 1);
  STAGE_OP(&Bs3[1][0], Bg, n0, 1);
  VMC4();
  BAR();

  int sl = 0;
  for (int u = 0; u < NT; ++u) {
    // stage tile u+2 into slot (sl+2)%3  (== slot of tile u-1; WAR-safe)
    if (u + 2 < NT) {
      const int s2 = (sl >= 1) ? sl - 1 : sl + 2;
      STAGE_OP(&As3[s2][0], Ag, m0, u + 2);
      STAGE_OP(&Bs3[s2][0], Bg, n0, u + 2);
    }
    const u16* Apb = &As3[sl][0];
    const u16* Bpb = &Bs3[sl][0];
    f16x8 a[8], b[4];
#pragma unroll
    for (int mf = 0; mf < 8; ++mf) a[mf] = *(const f16x8*)(Apb + offA[mf]);
#pragma unroll
    for (int nf = 0; nf < 4; ++nf) b[nf] = *(const f16x8*)(Bpb + offB[nf]);
    LGKM0();
    __builtin_amdgcn_s_setprio(1);
#pragma unroll
    for (int mf = 0; mf < 8; ++mf)
#pragma unroll
      for (int nf = 0; nf < 4; ++nf)
        acc[mf][nf] = mfma16h(a[mf], b[nf], acc[mf][nf]);
    __builtin_amdgcn_s_setprio(0);
    if (EPI == 1 && wn == 0) {
#pragma unroll
      for (int mf = 0; mf < 8; ++mf) {
        const f16x2* pr = (const f16x2*)&a[mf];
#pragma unroll
        for (int j = 0; j < 4; ++j)
          lsa[mf >> 2][mf & 3] = fdot2_(pr[j], ones2, lsa[mf >> 2][mf & 3]);
      }
    }
    SB0();
    if (u + 2 < NT) { VMC4(); }
    else if (u + 2 == NT) { VMC0(); }
    BAR();
    sl = (sl == 2) ? 0 : sl + 1;
  }
#undef STAGE_OP
#undef BAR
#undef LGKM0
#undef SB0
#undef VMC4
#undef VMC0

  // ---------------- epilogues (wave tile rows wm*128, cols wn*64) ----------------
  if (EPI == 2) {
    float bv[4];
#pragma unroll
    for (int cf = 0; cf < 4; ++cf) bv[cf] = bias[n0 + wn * 64 + cf * 16 + l15];
    const int region = n0 >> 10;
    const int ncol0 = (n0 & 1023) + wn * 64;
    if (region < 2) {
      u16* dst = region ? D1 : D0;
#pragma unroll
      for (int rf = 0; rf < 8; ++rf) {
        const int m = m0 + wm * 128 + rf * 16 + lhi * 4;
#pragma unroll
        for (int r = 0; r < 4; ++r)
#pragma unroll
          for (int cf = 0; cf < 4; ++cf)
            dst[(size_t)(m + r) * 1024 + ncol0 + cf * 16 + l15] = h1(acc[rf][cf][r] + bv[cf]);
      }
    } else {
#pragma unroll
      for (int rf = 0; rf < 8; ++rf) {
        const int m = m0 + wm * 128 + rf * 16 + lhi * 4;
        const int bb = m >> 12, s = m & 4095;
#pragma unroll
        for (int cf = 0; cf < 4; ++cf) {
          const int dcol = ncol0 + cf * 16 + l15;
          uint2 v;
          v.x = pk2h(acc[rf][cf][0] + bv[cf], acc[rf][cf][1] + bv[cf]);
          v.y = pk2h(acc[rf][cf][2] + bv[cf], acc[rf][cf][3] + bv[cf]);
          *(uint2*)&D2[(size_t)(bb * 1024 + dcol) * 4096 + s] = v;
        }
      }
    }
  } else if (EPI == 0) {
    // p = exp(acc/32), f16-clamped, store (row sums computed in gemm3)
#pragma unroll
    for (int rf = 0; rf < 8; ++rf) {
      const int m = m0 + wm * 128 + rf * 16 + lhi * 4;
#pragma unroll
      for (int r = 0; r < 4; ++r)
#pragma unroll
        for (int cf = 0; cf < 4; ++cf) {
          const int n = n0 + wn * 64 + cf * 16 + l15;
          float p = fminf(EXP2F(acc[rf][cf][r] * FA_C32), 60000.f);
          D0[(size_t)blockIdx.z * strC + (size_t)(m + r) * ldc + n] = h1(p);
        }
    }
  } else {
    // publish row sums (lanes hold rows at l15; C rows live at lhi*4+r)
    if (wn == 0) {
#pragma unroll
      for (int mh = 0; mh < 2; ++mh)
#pragma unroll
        for (int mf = 0; mf < 4; ++mf) {
          float s = lsa[mh][mf];
          s += __shfl_xor(s, 16, 64);
          s += __shfl_xor(s, 32, 64);
          if (lhi == 0) lds_l[wm * 128 + mh * 64 + mf * 16 + l15] = s;
        }
    }
    __syncthreads();
#pragma unroll
    for (int rf = 0; rf < 8; ++rf) {
      const int m = m0 + wm * 128 + rf * 16 + lhi * 4;
#pragma unroll
      for (int r = 0; r < 4; ++r) {
        const float li = 1.0f / lds_l[wm * 128 + rf * 16 + lhi * 4 + r];
#pragma unroll
        for (int cf = 0; cf < 4; ++cf) {
          const int n = n0 + wn * 64 + cf * 16 + l15;
          Df[(size_t)blockIdx.z * strC + (size_t)(m + r) * ldc + n] = acc[rf][cf][r] * li;
        }
      }
    }
  }
}

// ---------------- host ----------------
extern "C" void kernel_launch(void* const* d_in, const int* in_sizes, int n_in,
                              void* d_out, int out_size, void* d_ws, size_t ws_size,
                              hipStream_t stream) {
  const float* X = (const float*)d_in[0];   // [4,4096,1024]
  const float* W = (const float*)d_in[1];   // [3072,1024]
  const float* b = (const float*)d_in[2];   // [3072]
  float* out = (float*)d_out;               // [4,4096,1024] fp32
  char* ws = (char*)d_ws;

  const size_t SB = (size_t)4096 * 4096 * 2;          // S bytes per batch
  const size_t QB = (size_t)4096 * 1024 * 2;
  const size_t WFB = (size_t)3072 * 1024 * 2;
  int NB = 1;
  if (ws_size >= 4 * SB + WFB + 12 * QB) NB = 4;
  else if (ws_size >= 2 * SB + WFB + 12 * QB) NB = 2;

  u16* S  = (u16*)(ws);
  u16* Xf = (u16*)(ws);                               // overlay; dead after QKV proj
  u16* Wf = (u16*)(ws + (size_t)NB * SB);
  u16* Qf = (u16*)(ws + (size_t)NB * SB + WFB);
  u16* Kf = (u16*)(ws + (size_t)NB * SB + WFB + 4 * QB);
  u16* Vt = (u16*)(ws + (size_t)NB * SB + WFB + 8 * QB);

  // fused X+W cast: 16777216/8 + 3145728/8 = 2,490,368 items
  const int nX8 = 16777216 / 8, nTot8 = nX8 + 3145728 / 8;
  cast_f16_k<<<(nTot8 + 255) / 256, 256, 0, stream>>>(X, Xf, W, Wf, nX8, nTot8);

  // QKV projection: M=16384, N=3072, K=1024
  gemm8p<1024, 2><<<dim3(64, 12, 1), 512, 0, stream>>>(
      Xf, Wf, b, Qf, Kf, Vt, nullptr, 0, 0, 0, 0);

  const size_t strQ = (size_t)4096 * 1024;
  const size_t strS = (size_t)4096 * 4096;
  const size_t strV = (size_t)1024 * 4096;
  for (int g = 0; g < 4; g += NB) {
    const u16* Qg = Qf + (size_t)g * strQ;
    const u16* Kg = Kf + (size_t)g * strQ;
    const u16* Vg = Vt + (size_t)g * strV;
    float* Og = out + (size_t)g * strQ;
    // S = exp(Q K^T / 32)  [4096x4096] x NB
    gemm8p<1024, 0><<<dim3(16, 16, NB), 512, 0, stream>>>(
        Qg, Kg, nullptr, S, nullptr, nullptr, nullptr, 4096, strQ, strQ, strS);
    // O = (S Vt^T) / rowsum(S)  [4096x1024] x NB  (rowsum fused via fdot2)
    gemm8p<4096, 1><<<dim3(16, 4, NB), 512, 0, stream>>>(
        S, Vg, nullptr, nullptr, nullptr, nullptr, Og, 1024, strS, strV, strQ);
  }
}

// Round 18
// 391.063 us; speedup vs baseline: 1.2368x; 1.2368x over previous
//
#include <hip/hip_runtime.h>
#include <hip/hip_bf16.h>

typedef unsigned short u16;
typedef _Float16 f16x8 __attribute__((ext_vector_type(8)));
typedef _Float16 f16x2 __attribute__((ext_vector_type(2)));
typedef float f32x4 __attribute__((ext_vector_type(4)));

#if __has_builtin(__builtin_amdgcn_exp2f)
#define EXP2F(x) __builtin_amdgcn_exp2f(x)
#else
#define EXP2F(x) exp2f(x)
#endif
// log2(e)/32 : p = exp2(acc * FA_C32) = exp(acc/32)
#define FA_C32 0.045084220027780106f

__device__ __forceinline__ f32x4 mfma16h(f16x8 a, f16x8 b, f32x4 c) {
  return __builtin_amdgcn_mfma_f32_16x16x32_f16(a, b, c, 0, 0, 0);
}
__device__ __forceinline__ unsigned pk2h(float a, float b) {
  union { _Float16 h[2]; unsigned u; } x;
  x.h[0] = (_Float16)a; x.h[1] = (_Float16)b;
  return x.u;
}
__device__ __forceinline__ u16 h1(float a) {
  union { _Float16 h; u16 u; } x; x.h = (_Float16)a; return x.u;
}

#if __has_builtin(__builtin_amdgcn_fdot2)
__device__ __forceinline__ float fdot2_(f16x2 a, f16x2 b, float c) {
  return __builtin_amdgcn_fdot2(a, b, c, false);
}
#else
__device__ __forceinline__ float fdot2_(f16x2 a, f16x2 b, float c) {
  return c + (float)a[0] * (float)b[0] + (float)a[1] * (float)b[1];
}
#endif

typedef __attribute__((address_space(1))) const unsigned int gas_u32;
typedef __attribute__((address_space(3))) unsigned int las_u32;
__device__ __forceinline__ void gl_lds16(const u16* g, u16* l) {
  __builtin_amdgcn_global_load_lds((gas_u32*)g, (las_u32*)l, 16, 0, 0);
}

// ---------------- fused cast fp32 -> f16 for X then W, 8 elems/thread ----------------
__global__ __launch_bounds__(256) void cast_f16_k(const float* __restrict__ X,
                                                  u16* __restrict__ Xf,
                                                  const float* __restrict__ W,
                                                  u16* __restrict__ Wf,
                                                  int nX8, int nTot8) {
  int i = blockIdx.x * 256 + threadIdx.x;
  if (i >= nTot8) return;
  const float4* s4;
  uint4* d4;
  if (i < nX8) {
    s4 = (const float4*)X + i * 2;
    d4 = (uint4*)Xf + i;
  } else {
    s4 = (const float4*)W + (i - nX8) * 2;
    d4 = (uint4*)Wf + (i - nX8);
  }
  float4 a = s4[0], b = s4[1];
  uint4 o;
  o.x = pk2h(a.x, a.y); o.y = pk2h(a.z, a.w);
  o.z = pk2h(b.x, b.y); o.w = pk2h(b.z, b.w);
  *d4 = o;
}

// =================================================================
// FINAL (= round-14/16 K-loop, session-best 391 us, reproduced twice).
// 3-phase GEMM: BM=BN=256, BK=64, 8 waves (2Mx4N), acc 8x4,
// quarter-granularity staging (round-9 WAR ledger).
// Per tile u (dbuf d=u&1), 3 phases:
//   phA: read a0(8),b0(4) | stage A q1,q3 of u+1 (dbuf d^1) | BAR lgkm0 |
//        16 MFMA (a0,b0)
//   phB: read b1(4)       | stage A q0,q2 of u+2 | BAR lgkm0 | 16 MFMA (a0,b1)
//   phC: read a1(8)       | stage B q0..q3 of u+2 | BAR lgkm0 |
//        32 MFMA (a1,b1 + a1,b0) | vmcnt(6) (0 at tail) | BAR
// WAR: every stage's target was last ds_read in a strictly earlier phase and
// serviced by that phase's lgkmcnt(0) BEFORE its closing barrier.
// vmcnt FIFO: drain-to-6 completes tile u+1, keeps tile u+2's 6 in flight.
//   EPI=0: D0 f16 = exp(acc/32) (clamped)
//   EPI=1: Df f32 = acc / l_row  (l via fdot2 on A-fragments, wn==0 waves)
//   EPI=2: QKV scatter (Q,K row-major; V -> Vt[b][d][s])
// Measured local optimum of this structure class (MI355X):
//   r10 XCD-swizzle+SB0-removal: hurt/null | r15 counted-lgkm 2-bar: -4%
//   r17 ring-3 BK=32 1-bar: -24%.  41% MfmaUtil = barrier-lockstep
//   serialization of block-wide LDS-read burst with MFMA burst.
// =================================================================
template <int K_, int EPI>
__global__ __launch_bounds__(512, 1) void gemm8p(
    const u16* __restrict__ A, const u16* __restrict__ B,
    const float* __restrict__ bias, u16* __restrict__ D0, u16* __restrict__ D1,
    u16* __restrict__ D2, float* __restrict__ Df, const int ldc,
    const size_t strA, const size_t strB, const size_t strC) {
  constexpr int NT = K_ / 64;
  static_assert(NT >= 4 && (NT % 2) == 0, "need even NT >= 4");
  __shared__ __align__(16) u16 As[2][2][128 * 64];   // [dbuf][M-half]
  __shared__ __align__(16) u16 Bs[2][2][128 * 64];   // [dbuf][N-half]
  __shared__ float lds_l[256];                       // EPI=1 row sums

  const int tid = threadIdx.x, lane = tid & 63, wid = tid >> 6;
  const int l15 = lane & 15, lhi = lane >> 4;
  const int m0 = blockIdx.x * 256, n0 = blockIdx.y * 256;
  const int wm = wid >> 2, wn = wid & 3;
  const u16* Ag = A + (size_t)blockIdx.z * strA;
  const u16* Bg = B + (size_t)blockIdx.z * strB;

  const int srow8 = lane >> 3;              // LDS row & 7 for this lane's 16B
  const int sblk = (lane & 7) ^ srow8;      // source block XOR (T2 both-sides)

// one 64-row quarter: 1 global_load_lds per wave (8 rows/wave)
#define STAGE_Q(BUF, G, GROW0, ST)                                        \
  gl_lds16((G) + (size_t)((GROW0) + wid * 8 + srow8) * K_ +               \
               (ST) * 64 + sblk * 8,                                      \
           (BUF) + (wid * 8) * 64)

#define BAR()                                                             \
  asm volatile("" ::: "memory");                                          \
  __builtin_amdgcn_s_barrier();                                           \
  asm volatile("" ::: "memory")

#define LGKM0()                                                           \
  asm volatile("s_waitcnt lgkmcnt(0)" ::: "memory");                      \
  __builtin_amdgcn_sched_barrier(0)

#define SB0() __builtin_amdgcn_sched_barrier(0)
#define VMC6() asm volatile("s_waitcnt vmcnt(6)" ::: "memory")
#define VMC0() asm volatile("s_waitcnt vmcnt(0)" ::: "memory")

#define RD_A(DST, PB, MH)                                                 \
  _Pragma("unroll") for (int mf = 0; mf < 4; ++mf)                        \
  _Pragma("unroll") for (int ks = 0; ks < 2; ++ks)                        \
    DST[mf][ks] = *(const f16x8*)((PB) + ((MH) * 64 + mf * 16 + l15) * 64 \
                                  + (((ks * 4 + lhi) ^ (l15 & 7)) * 8));

#define RD_B(DST, PB, BO, NH)                                             \
  _Pragma("unroll") for (int nf = 0; nf < 2; ++nf)                        \
  _Pragma("unroll") for (int ks = 0; ks < 2; ++ks)                        \
    DST[nf][ks] = *(const f16x8*)((PB) + ((BO) + (NH) * 32 + nf * 16 + l15) * 64 \
                                  + (((ks * 4 + lhi) ^ (l15 & 7)) * 8));

#define MM(AV, BV, MB, NB2)                                               \
  __builtin_amdgcn_s_setprio(1);                                          \
  _Pragma("unroll") for (int mf = 0; mf < 4; ++mf)                        \
  _Pragma("unroll") for (int nf = 0; nf < 2; ++nf)                        \
  _Pragma("unroll") for (int ks = 0; ks < 2; ++ks)                        \
    acc[(MB) * 4 + mf][(NB2) * 2 + nf] =                                  \
        mfma16h(AV[mf][ks], BV[nf][ks], acc[(MB) * 4 + mf][(NB2) * 2 + nf]); \
  __builtin_amdgcn_s_setprio(0);

// row-sum accumulate over an A fragment set (EPI=1, wn==0 waves only)
#define SUMA(FR, MH8)                                                     \
  if (EPI == 1 && wn == 0) {                                              \
    _Pragma("unroll") for (int mf = 0; mf < 4; ++mf)                      \
    _Pragma("unroll") for (int ks = 0; ks < 2; ++ks) {                    \
      const f16x2* _pr = (const f16x2*)&FR[mf][ks];                       \
      _Pragma("unroll") for (int j = 0; j < 4; ++j)                       \
        lsa[MH8][mf] = fdot2_(_pr[j], ones2, lsa[MH8][mf]);               \
    }                                                                     \
  }

  f32x4 acc[8][4];
#pragma unroll
  for (int i = 0; i < 8; ++i)
#pragma unroll
    for (int j = 0; j < 4; ++j) acc[i][j] = 0.f;

  float lsa[2][4];
#pragma unroll
  for (int i = 0; i < 2; ++i)
#pragma unroll
    for (int j = 0; j < 4; ++j) lsa[i][j] = 0.f;
  const f16x2 ones2 = {(_Float16)1.0f, (_Float16)1.0f};

  const int bofs = (wn & 1) * 64;

  // prologue: tile0 full (8 loads); tile1 A02+B (6 loads; A13(1) comes from
  // u=0's phA per schedule). vmcnt(6) drains tile0, keeps tile1's 6.
  STAGE_Q(&As[0][0][0],    Ag, m0,       0);
  STAGE_Q(&As[0][0][4096], Ag, m0 + 64,  0);
  STAGE_Q(&As[0][1][0],    Ag, m0 + 128, 0);
  STAGE_Q(&As[0][1][4096], Ag, m0 + 192, 0);
  STAGE_Q(&Bs[0][0][0],    Bg, n0,       0);
  STAGE_Q(&Bs[0][0][4096], Bg, n0 + 64,  0);
  STAGE_Q(&Bs[0][1][0],    Bg, n0 + 128, 0);
  STAGE_Q(&Bs[0][1][4096], Bg, n0 + 192, 0);
  STAGE_Q(&As[1][0][0],    Ag, m0,       1);
  STAGE_Q(&As[1][1][0],    Ag, m0 + 128, 1);
  STAGE_Q(&Bs[1][0][0],    Bg, n0,       1);
  STAGE_Q(&Bs[1][0][4096], Bg, n0 + 64,  1);
  STAGE_Q(&Bs[1][1][0],    Bg, n0 + 128, 1);
  STAGE_Q(&Bs[1][1][4096], Bg, n0 + 192, 1);
  VMC6();
  BAR();

#pragma unroll 2
  for (int u = 0; u < NT; ++u) {
    const int d = u & 1;
    const u16* Apb = &As[d][wm][0];
    const u16* Bpb = &Bs[d][wn >> 1][0];
    f16x8 a0[4][2], a1[4][2], b0[2][2], b1[2][2];

    // ---- phA: read a0,b0; stage A q1,q3 of u+1 (other dbuf) ----
    RD_A(a0, Apb, 0);
    RD_B(b0, Bpb, bofs, 0);
    if (u + 1 < NT) {
      STAGE_Q(&As[d ^ 1][0][4096], Ag, m0 + 64,  u + 1);
      STAGE_Q(&As[d ^ 1][1][4096], Ag, m0 + 192, u + 1);
    }
    BAR();
    LGKM0();
    MM(a0, b0, 0, 0);
    SUMA(a0, 0);
    SB0();
    BAR();

    // ---- phB: read b1; stage A q0,q2 of u+2 (same dbuf) ----
    RD_B(b1, Bpb, bofs, 1);
    if (u + 2 < NT) {
      STAGE_Q(&As[d][0][0], Ag, m0,       u + 2);
      STAGE_Q(&As[d][1][0], Ag, m0 + 128, u + 2);
    }
    BAR();
    LGKM0();
    MM(a0, b1, 0, 1);
    SB0();
    BAR();

    // ---- phC: read a1; stage B q0..q3 of u+2; 32 MFMA; boundary vmcnt ----
    RD_A(a1, Apb, 1);
    if (u + 2 < NT) {
      STAGE_Q(&Bs[d][0][0],    Bg, n0,       u + 2);
      STAGE_Q(&Bs[d][0][4096], Bg, n0 + 64,  u + 2);
      STAGE_Q(&Bs[d][1][0],    Bg, n0 + 128, u + 2);
      STAGE_Q(&Bs[d][1][4096], Bg, n0 + 192, u + 2);
    }
    BAR();
    LGKM0();
    MM(a1, b1, 1, 1);
    SUMA(a1, 1);
    MM(a1, b0, 1, 0);
    SB0();
    if (u + 2 < NT) { VMC6(); }
    else if (u + 2 == NT) { VMC0(); }
    BAR();
  }
#undef STAGE_Q
#undef BAR
#undef LGKM0
#undef SB0
#undef VMC6
#undef VMC0
#undef RD_A
#undef RD_B
#undef MM
#undef SUMA

  // ---------------- epilogues (wave tile rows wm*128, cols wn*64) ----------------
  if (EPI == 2) {
    float bv[4];
#pragma unroll
    for (int cf = 0; cf < 4; ++cf) bv[cf] = bias[n0 + wn * 64 + cf * 16 + l15];
    const int region = n0 >> 10;
    const int ncol0 = (n0 & 1023) + wn * 64;
    if (region < 2) {
      u16* dst = region ? D1 : D0;
#pragma unroll
      for (int rf = 0; rf < 8; ++rf) {
        const int m = m0 + wm * 128 + rf * 16 + lhi * 4;
#pragma unroll
        for (int r = 0; r < 4; ++r)
#pragma unroll
          for (int cf = 0; cf < 4; ++cf)
            dst[(size_t)(m + r) * 1024 + ncol0 + cf * 16 + l15] = h1(acc[rf][cf][r] + bv[cf]);
      }
    } else {
#pragma unroll
      for (int rf = 0; rf < 8; ++rf) {
        const int m = m0 + wm * 128 + rf * 16 + lhi * 4;
        const int bb = m >> 12, s = m & 4095;
#pragma unroll
        for (int cf = 0; cf < 4; ++cf) {
          const int dcol = ncol0 + cf * 16 + l15;
          uint2 v;
          v.x = pk2h(acc[rf][cf][0] + bv[cf], acc[rf][cf][1] + bv[cf]);
          v.y = pk2h(acc[rf][cf][2] + bv[cf], acc[rf][cf][3] + bv[cf]);
          *(uint2*)&D2[(size_t)(bb * 1024 + dcol) * 4096 + s] = v;
        }
      }
    }
  } else if (EPI == 0) {
    // p = exp(acc/32), f16-clamped, store (row sums computed in gemm3)
#pragma unroll
    for (int rf = 0; rf < 8; ++rf) {
      const int m = m0 + wm * 128 + rf * 16 + lhi * 4;
#pragma unroll
      for (int r = 0; r < 4; ++r)
#pragma unroll
        for (int cf = 0; cf < 4; ++cf) {
          const int n = n0 + wn * 64 + cf * 16 + l15;
          float p = fminf(EXP2F(acc[rf][cf][r] * FA_C32), 60000.f);
          D0[(size_t)blockIdx.z * strC + (size_t)(m + r) * ldc + n] = h1(p);
        }
    }
  } else {
    // publish row sums (lanes hold rows at l15; C rows live at lhi*4+r)
    if (wn == 0) {
#pragma unroll
      for (int mh = 0; mh < 2; ++mh)
#pragma unroll
        for (int mf = 0; mf < 4; ++mf) {
          float s = lsa[mh][mf];
          s += __shfl_xor(s, 16, 64);
          s += __shfl_xor(s, 32, 64);
          if (lhi == 0) lds_l[wm * 128 + mh * 64 + mf * 16 + l15] = s;
        }
    }
    __syncthreads();
#pragma unroll
    for (int rf = 0; rf < 8; ++rf) {
      const int m = m0 + wm * 128 + rf * 16 + lhi * 4;
#pragma unroll
      for (int r = 0; r < 4; ++r) {
        const float li = 1.0f / lds_l[wm * 128 + rf * 16 + lhi * 4 + r];
#pragma unroll
        for (int cf = 0; cf < 4; ++cf) {
          const int n = n0 + wn * 64 + cf * 16 + l15;
          Df[(size_t)blockIdx.z * strC + (size_t)(m + r) * ldc + n] = acc[rf][cf][r] * li;
        }
      }
    }
  }
}

// ---------------- host ----------------
extern "C" void kernel_launch(void* const* d_in, const int* in_sizes, int n_in,
                              void* d_out, int out_size, void* d_ws, size_t ws_size,
                              hipStream_t stream) {
  const float* X = (const float*)d_in[0];   // [4,4096,1024]
  const float* W = (const float*)d_in[1];   // [3072,1024]
  const float* b = (const float*)d_in[2];   // [3072]
  float* out = (float*)d_out;               // [4,4096,1024] fp32
  char* ws = (char*)d_ws;

  const size_t SB = (size_t)4096 * 4096 * 2;          // S bytes per batch
  const size_t QB = (size_t)4096 * 1024 * 2;
  const size_t WFB = (size_t)3072 * 1024 * 2;
  int NB = 1;
  if (ws_size >= 4 * SB + WFB + 12 * QB) NB = 4;
  else if (ws_size >= 2 * SB + WFB + 12 * QB) NB = 2;

  u16* S  = (u16*)(ws);
  u16* Xf = (u16*)(ws);                               // overlay; dead after QKV proj
  u16* Wf = (u16*)(ws + (size_t)NB * SB);
  u16* Qf = (u16*)(ws + (size_t)NB * SB + WFB);
  u16* Kf = (u16*)(ws + (size_t)NB * SB + WFB + 4 * QB);
  u16* Vt = (u16*)(ws + (size_t)NB * SB + WFB + 8 * QB);

  // fused X+W cast: 16777216/8 + 3145728/8 = 2,490,368 items
  const int nX8 = 16777216 / 8, nTot8 = nX8 + 3145728 / 8;
  cast_f16_k<<<(nTot8 + 255) / 256, 256, 0, stream>>>(X, Xf, W, Wf, nX8, nTot8);

  // QKV projection: M=16384, N=3072, K=1024
  gemm8p<1024, 2><<<dim3(64, 12, 1), 512, 0, stream>>>(
      Xf, Wf, b, Qf, Kf, Vt, nullptr, 0, 0, 0, 0);

  const size_t strQ = (size_t)4096 * 1024;
  const size_t strS = (size_t)4096 * 4096;
  const size_t strV = (size_t)1024 * 4096;
  for (int g = 0; g < 4; g += NB) {
    const u16* Qg = Qf + (size_t)g * strQ;
    const u16* Kg = Kf + (size_t)g * strQ;
    const u16* Vg = Vt + (size_t)g * strV;
    float* Og = out + (size_t)g * strQ;
    // S = exp(Q K^T / 32)  [4096x4096] x NB
    gemm8p<1024, 0><<<dim3(16, 16, NB), 512, 0, stream>>>(
        Qg, Kg, nullptr, S, nullptr, nullptr, nullptr, 4096, strQ, strQ, strS);
    // O = (S Vt^T) / rowsum(S)  [4096x1024] x NB  (rowsum fused via fdot2)
    gemm8p<4096, 1><<<dim3(16, 4, NB), 512, 0, stream>>>(
        S, Vg, nullptr, nullptr, nullptr, nullptr, Og, 1024, strS, strV, strQ);
  }
}